// Round 3
// baseline (790.350 us; speedup 1.0000x reference)
//
#include <hip/hip_runtime.h>

#define N_NODES   50000
#define N_EDGES   800000
#define IN_DIM    128
#define HID_DIM   256
#define OUT_DIM   64
#define N_CLASSES 40

typedef __attribute__((ext_vector_type(8))) short short8;
typedef __attribute__((ext_vector_type(8))) unsigned short ushort8;
typedef __attribute__((ext_vector_type(4))) float f32x4;

__device__ inline short f2bf(float x) {
    unsigned u = __builtin_bit_cast(unsigned, x);
    unsigned r = (u + 0x7FFFu + ((u >> 16) & 1u)) >> 16;
    return (short)r;
}
__device__ inline float bf2f(unsigned short u) {
    unsigned v = ((unsigned)u) << 16;
    return __builtin_bit_cast(float, v);
}

// ---------------- degree / normalization / CSR ----------------

__global__ void k_deg_count(const int* __restrict__ dst, int* __restrict__ degi) {
    int e = blockIdx.x * 256 + threadIdx.x;
    if (e < N_EDGES) atomicAdd(&degi[dst[e]], 1);
}

__global__ void k_dinv(const int* __restrict__ degi, float* __restrict__ dinv) {
    int v = blockIdx.x * 256 + threadIdx.x;
    if (v < N_NODES) dinv[v] = rsqrtf((float)(degi[v] + 1));
}

__global__ void k_scan_bsum(const int* __restrict__ vals, int n, int* __restrict__ bsum) {
    __shared__ int sm[256];
    int t = threadIdx.x, i = blockIdx.x * 256 + t;
    sm[t] = (i < n) ? vals[i] : 0;
    __syncthreads();
    for (int s = 128; s > 0; s >>= 1) {
        if (t < s) sm[t] += sm[t + s];
        __syncthreads();
    }
    if (t == 0) bsum[blockIdx.x] = sm[0];
}

__global__ void k_scan_bscan(int* __restrict__ bsum, int nb) {
    __shared__ int sm[256];
    int t = threadIdx.x;
    int orig = (t < nb) ? bsum[t] : 0;
    sm[t] = orig;
    __syncthreads();
    for (int off = 1; off < 256; off <<= 1) {
        int v = (t >= off) ? sm[t - off] : 0;
        __syncthreads();
        sm[t] += v;
        __syncthreads();
    }
    if (t < nb) bsum[t] = sm[t] - orig;
}

__global__ void k_scan_final(const int* __restrict__ vals, int n,
                             const int* __restrict__ bscan, int* __restrict__ out) {
    __shared__ int sm[256];
    int t = threadIdx.x, i = blockIdx.x * 256 + t;
    int orig = (i < n) ? vals[i] : 0;
    sm[t] = orig;
    __syncthreads();
    for (int off = 1; off < 256; off <<= 1) {
        int v = (t >= off) ? sm[t - off] : 0;
        __syncthreads();
        sm[t] += v;
        __syncthreads();
    }
    int excl = sm[t] - orig + bscan[blockIdx.x];
    if (i < n) out[i] = excl;
    if (i == n - 1) out[n] = excl + orig;
}

__global__ void k_csr_fill(const int* __restrict__ src, const int* __restrict__ dst,
                           const int* __restrict__ csr_off, int* __restrict__ cursor,
                           int* __restrict__ csr_src) {
    int e = blockIdx.x * 256 + threadIdx.x;
    if (e < N_EDGES) {
        int d = dst[e];
        int pos = csr_off[d] + atomicAdd(&cursor[d], 1);
        csr_src[pos] = src[e];
    }
}

// ---------------- weight prep: fp32 [K][N] -> bf16 [N][K] ----------------

__global__ void k_prep_w(const float* __restrict__ W1, const float* __restrict__ W2,
                         const float* __restrict__ Wp1, const float* __restrict__ Wp2,
                         short* __restrict__ W1t, short* __restrict__ W2t,
                         short* __restrict__ Wp1t, short* __restrict__ Wp2t) {
    int i = blockIdx.x * 256 + threadIdx.x;
    if (i < 128 * 256) {  // [128][256] -> [256][128]
        int k = i >> 8, n = i & 255;
        W1t[n * 128 + k]  = f2bf(W1[i]);
        Wp1t[n * 128 + k] = f2bf(Wp1[i]);
    }
    if (i < 256 * 64) {   // [256][64] -> [64][256]
        int k = i >> 6, o = i & 63;
        W2t[o * 256 + k]  = f2bf(W2[i]);
        Wp2t[o * 256 + k] = f2bf(Wp2[i]);
    }
}

__global__ void k_copy_ei(const int* __restrict__ ei, float* __restrict__ out) {
    int j = blockIdx.x * 256 + threadIdx.x;  // int4 -> float4
    if (j < (2 * N_EDGES) / 4) {
        int4 v = ((const int4*)ei)[j];
        float4 o = {(float)v.x, (float)v.y, (float)v.z, (float)v.w};
        ((float4*)out)[j] = o;
    }
}

// ---------------- GEMM1: h1lin[n][256] = x[n][128] @ W1  (bf16 MFMA, transposed D) ----

__global__ __launch_bounds__(256) void k_gemm1_mfma(const float* __restrict__ x,
                                                    const short* __restrict__ W1t,
                                                    unsigned short* __restrict__ h1lin) {
    __shared__ unsigned short xs[64 * 128];  // 16 KB, row stride 256 B, swizzled
    const int t = threadIdx.x;
    const int lane = t & 63, wv = t >> 6, lr = lane & 15, lg = lane >> 4;
    const int nb = blockIdx.x * 64;

    #pragma unroll
    for (int i = 0; i < 8; i++) {
        int q = t + i * 256;          // float4 slot: 64 rows x 32
        int row = q >> 5, seg = q & 31;
        int node = nb + row;
        float4 v = {0.f, 0.f, 0.f, 0.f};
        if (node < N_NODES) v = ((const float4*)x)[(size_t)node * 32 + seg];
        ushort4 u;
        u.x = (unsigned short)f2bf(v.x); u.y = (unsigned short)f2bf(v.y);
        u.z = (unsigned short)f2bf(v.z); u.w = (unsigned short)f2bf(v.w);
        *(ushort4*)((char*)xs + ((row * 256 + seg * 8) ^ ((row & 7) << 4))) = u;
    }
    __syncthreads();

    short8 A1[4][4];  // W1t rows = hidden wv*64+mi*16+lr
    #pragma unroll
    for (int mi = 0; mi < 4; mi++)
        #pragma unroll
        for (int kt = 0; kt < 4; kt++)
            A1[mi][kt] = *(const short8*)(W1t + (size_t)(wv * 64 + mi * 16 + lr) * 128 + kt * 32 + lg * 8);

    #pragma unroll
    for (int nj = 0; nj < 4; nj++) {
        short8 Bf[4];
        int nr = nj * 16 + lr;
        #pragma unroll
        for (int kt = 0; kt < 4; kt++)
            Bf[kt] = *(const short8*)((const char*)xs + ((nr * 256 + kt * 64 + lg * 16) ^ ((nr & 7) << 4)));
        int node = nb + nr;
        #pragma unroll
        for (int mi = 0; mi < 4; mi++) {
            f32x4 acc = {0.f, 0.f, 0.f, 0.f};
            #pragma unroll
            for (int kt = 0; kt < 4; kt++)
                acc = __builtin_amdgcn_mfma_f32_16x16x32_bf16(A1[mi][kt], Bf[kt], acc, 0, 0, 0);
            if (node < N_NODES) {
                ushort4 u;
                u.x = (unsigned short)f2bf(acc[0]); u.y = (unsigned short)f2bf(acc[1]);
                u.z = (unsigned short)f2bf(acc[2]); u.w = (unsigned short)f2bf(acc[3]);
                *(ushort4*)(h1lin + (size_t)node * 256 + wv * 64 + mi * 16 + lg * 4) = u;
            }
        }
    }
}

// ---------------- GEMM2: h2lin[n][64] = h1[n][256] @ W2  (fp32 out, transposed D) ----

__global__ __launch_bounds__(256) void k_gemm2_mfma(const unsigned short* __restrict__ h1,
                                                    const short* __restrict__ W2t,
                                                    float* __restrict__ h2lin) {
    __shared__ unsigned short hs[64 * 256];  // 32 KB, row stride 512 B, swizzled
    const int t = threadIdx.x;
    const int lane = t & 63, wv = t >> 6, lr = lane & 15, lg = lane >> 4;
    const int nb = blockIdx.x * 64;

    #pragma unroll
    for (int i = 0; i < 8; i++) {
        int q = t + i * 256;          // ushort8 slot: 64 rows x 32
        int row = q >> 5, seg = q & 31;
        int node = nb + row;
        ushort8 v = {0, 0, 0, 0, 0, 0, 0, 0};
        if (node < N_NODES) v = *(const ushort8*)(h1 + (size_t)node * 256 + seg * 8);
        *(ushort8*)((char*)hs + ((row * 512 + seg * 16) ^ ((row & 7) << 4))) = v;
    }
    __syncthreads();

    short8 Bh[8];
    int nr = wv * 16 + lr;
    #pragma unroll
    for (int kt = 0; kt < 8; kt++)
        Bh[kt] = *(const short8*)((const char*)hs + ((nr * 512 + kt * 64 + lg * 16) ^ ((nr & 7) << 4)));
    int node = nb + nr;
    #pragma unroll
    for (int mi = 0; mi < 4; mi++) {
        f32x4 acc = {0.f, 0.f, 0.f, 0.f};
        #pragma unroll
        for (int kt = 0; kt < 8; kt++) {
            short8 A2 = *(const short8*)(W2t + (size_t)(mi * 16 + lr) * 256 + kt * 32 + lg * 8);
            acc = __builtin_amdgcn_mfma_f32_16x16x32_bf16(A2, Bh[kt], acc, 0, 0, 0);
        }
        if (node < N_NODES) {
            float4 o = {acc[0], acc[1], acc[2], acc[3]};
            *(float4*)(h2lin + (size_t)node * 64 + mi * 16 + lg * 4) = o;
        }
    }
}

// ---------------- aggregation 1 (DIM=256 bf16): wave per node ----------------

__global__ __launch_bounds__(256) void k_agg1(const unsigned short* __restrict__ h,
                                              const float* __restrict__ dinv,
                                              const int* __restrict__ csr_off,
                                              const int* __restrict__ csr_src,
                                              const float* __restrict__ b1,
                                              unsigned short* __restrict__ out) {
    const int v = blockIdx.x * 4 + (threadIdx.x >> 6);
    const int lane = threadIdx.x & 63;
    float dv = dinv[v];
    ushort4 sv = *(const ushort4*)(h + (size_t)v * 256 + lane * 4);
    f32x4 acc = {bf2f(sv.x) * dv, bf2f(sv.y) * dv, bf2f(sv.z) * dv, bf2f(sv.w) * dv};
    int beg = csr_off[v], end = csr_off[v + 1];
    for (int base = beg; base < end; base += 64) {
        int idx = base + lane;
        int sj = (idx < end) ? csr_src[idx] : 0;
        float dj = (idx < end) ? dinv[sj] : 0.f;
        int m = min(64, end - base);
        for (int j = 0; j < m; j++) {
            int s = __shfl(sj, j);
            float ds = __shfl(dj, j);
            ushort4 hv = *(const ushort4*)(h + (size_t)s * 256 + lane * 4);
            acc[0] += bf2f(hv.x) * ds;
            acc[1] += bf2f(hv.y) * ds;
            acc[2] += bf2f(hv.z) * ds;
            acc[3] += bf2f(hv.w) * ds;
        }
    }
    float4 bv = *(const float4*)(b1 + lane * 4);
    ushort4 o;
    o.x = (unsigned short)f2bf(fmaxf(acc[0] * dv + bv.x, 0.f));
    o.y = (unsigned short)f2bf(fmaxf(acc[1] * dv + bv.y, 0.f));
    o.z = (unsigned short)f2bf(fmaxf(acc[2] * dv + bv.z, 0.f));
    o.w = (unsigned short)f2bf(fmaxf(acc[3] * dv + bv.w, 0.f));
    *(ushort4*)(out + (size_t)v * 256 + lane * 4) = o;
}

// ---------------- aggregation 2 (DIM=64 fp32): wave per node; writes f + fb(bf16) ----

__global__ __launch_bounds__(256) void k_agg2(const float* __restrict__ h,
                                              const float* __restrict__ dinv,
                                              const int* __restrict__ csr_off,
                                              const int* __restrict__ csr_src,
                                              const float* __restrict__ b2,
                                              float* __restrict__ f_out,
                                              unsigned short* __restrict__ fb) {
    const int v = blockIdx.x * 4 + (threadIdx.x >> 6);
    const int lane = threadIdx.x & 63;
    float dv = dinv[v];
    float acc = h[(size_t)v * 64 + lane] * dv;
    int beg = csr_off[v], end = csr_off[v + 1];
    for (int base = beg; base < end; base += 64) {
        int idx = base + lane;
        int sj = (idx < end) ? csr_src[idx] : 0;
        float dj = (idx < end) ? dinv[sj] : 0.f;
        int m = min(64, end - base);
        for (int j = 0; j < m; j++) {
            int s = __shfl(sj, j);
            float ds = __shfl(dj, j);
            acc += h[(size_t)s * 64 + lane] * ds;
        }
    }
    float r = acc * dv + b2[lane];
    f_out[(size_t)v * 64 + lane] = r;
    fb[(size_t)v * 64 + lane] = (unsigned short)f2bf(r);
}

// ---------------- classifier head: 16 nodes/block ----------------

__global__ __launch_bounds__(256) void k_logits(const float* __restrict__ f,
                                                const float* __restrict__ Wc,
                                                const float* __restrict__ bc,
                                                float* __restrict__ out) {
    __shared__ float fs[16 * 64];
    __shared__ float Wcs[64 * 40];
    __shared__ float bcs[40];
    const int t = threadIdx.x;
    const int nb = blockIdx.x * 16;
    {
        float4 v = ((const float4*)f)[(size_t)(nb + (t >> 4)) * 16 + (t & 15)];
        *(float4*)(fs + t * 4) = v;
    }
    #pragma unroll
    for (int k = 0; k < 10; k++) Wcs[t + k * 256] = Wc[t + k * 256];
    if (t < 40) bcs[t] = bc[t];
    __syncthreads();
    #pragma unroll
    for (int k = 0; k < 3; k++) {
        int idx = t + k * 256;
        if (idx < 640) {
            int n = idx / 40, cls = idx - n * 40;
            float acc = bcs[cls];
            #pragma unroll
            for (int i = 0; i < 64; i++) acc += fs[n * 64 + i] * Wcs[i * 40 + cls];
            out[(size_t)(nb + n) * 40 + cls] = acc;
        }
    }
}

// ---------------- fused edge MLP: persistent, async-staged, transposed-D MFMA ----

__global__ __launch_bounds__(256, 3) void k_edge_mlp3(
        const unsigned short* __restrict__ fb,
        const int* __restrict__ src, const int* __restrict__ dst,
        const short* __restrict__ Wp1t, const float* __restrict__ bp1,
        const short* __restrict__ Wp2t, const float* __restrict__ bp2,
        float* __restrict__ out, int n_tiles) {
    __shared__ unsigned short ef_s[64 * 128];   // 16 KB
    __shared__ unsigned short hid_s[64 * 256];  // 32 KB

    const int t = threadIdx.x;
    const int lane = t & 63, wv = t >> 6, lr = lane & 15, lg = lane >> 4;

    // hoisted L1 A-frags: Wp1t rows = hidden wv*64+mi*16+lr
    short8 A1[4][4];
    #pragma unroll
    for (int mi = 0; mi < 4; mi++)
        #pragma unroll
        for (int kt = 0; kt < 4; kt++)
            A1[mi][kt] = *(const short8*)(Wp1t + (size_t)(wv * 64 + mi * 16 + lr) * 128 + kt * 32 + lg * 8);

    ushort8 g[4];
    int tid = blockIdx.x;
    {   // prologue gather
        int e0 = tid * 64;
        #pragma unroll
        for (int i = 0; i < 4; i++) {
            int q = t + i * 256, el = q >> 4, seg = q & 15;
            int node = (seg < 8) ? src[e0 + el] : dst[e0 + el];
            g[i] = *(const ushort8*)(fb + (size_t)node * 64 + (seg & 7) * 8);
        }
    }

    for (; tid < n_tiles; tid += gridDim.x) {
        // write ef from regs
        #pragma unroll
        for (int i = 0; i < 4; i++) {
            int q = t + i * 256, el = q >> 4, seg = q & 15;
            *(ushort8*)((char*)ef_s + ((el * 256 + seg * 16) ^ ((el & 7) << 4))) = g[i];
        }
        __syncthreads();

        // issue next tile's gather early (hides under L1+L2 MFMA)
        int tnext = tid + gridDim.x;
        if (tnext < n_tiles) {
            int e0 = tnext * 64;
            #pragma unroll
            for (int i = 0; i < 4; i++) {
                int q = t + i * 256, el = q >> 4, seg = q & 15;
                int node = (seg < 8) ? src[e0 + el] : dst[e0 + el];
                g[i] = *(const ushort8*)(fb + (size_t)node * 64 + (seg & 7) * 8);
            }
        }

        // ---- L1: hidT = Wp1 x ef ----
        #pragma unroll
        for (int nj = 0; nj < 4; nj++) {
            short8 Bf[4];
            int er = nj * 16 + lr;
            #pragma unroll
            for (int kt = 0; kt < 4; kt++)
                Bf[kt] = *(const short8*)((const char*)ef_s + ((er * 256 + kt * 64 + lg * 16) ^ ((er & 7) << 4)));
            #pragma unroll
            for (int mi = 0; mi < 4; mi++) {
                f32x4 acc = {0.f, 0.f, 0.f, 0.f};
                #pragma unroll
                for (int kt = 0; kt < 4; kt++)
                    acc = __builtin_amdgcn_mfma_f32_16x16x32_bf16(A1[mi][kt], Bf[kt], acc, 0, 0, 0);
                float4 bv = *(const float4*)(bp1 + wv * 64 + mi * 16 + lg * 4);
                ushort4 h4;
                h4.x = (unsigned short)f2bf(fmaxf(acc[0] + bv.x, 0.f));
                h4.y = (unsigned short)f2bf(fmaxf(acc[1] + bv.y, 0.f));
                h4.z = (unsigned short)f2bf(fmaxf(acc[2] + bv.z, 0.f));
                h4.w = (unsigned short)f2bf(fmaxf(acc[3] + bv.w, 0.f));
                *(ushort4*)((char*)hid_s + ((er * 512 + (wv * 128 + mi * 32 + lg * 8)) ^ ((er & 7) << 4))) = h4;
            }
        }
        __syncthreads();

        // ---- L2: outT = Wp2 x hid ----
        {
            short8 Bh[8];
            int er = wv * 16 + lr;
            #pragma unroll
            for (int kt = 0; kt < 8; kt++)
                Bh[kt] = *(const short8*)((const char*)hid_s + ((er * 512 + kt * 64 + lg * 16) ^ ((er & 7) << 4)));
            #pragma unroll
            for (int mi = 0; mi < 4; mi++) {
                f32x4 acc = {0.f, 0.f, 0.f, 0.f};
                #pragma unroll
                for (int kt = 0; kt < 8; kt++) {
                    short8 A2 = *(const short8*)(Wp2t + (size_t)(mi * 16 + lr) * 256 + kt * 32 + lg * 8);
                    acc = __builtin_amdgcn_mfma_f32_16x16x32_bf16(A2, Bh[kt], acc, 0, 0, 0);
                }
                float4 bv = *(const float4*)(bp2 + mi * 16 + lg * 4);
                float4 o = {acc[0] + bv.x, acc[1] + bv.y, acc[2] + bv.z, acc[3] + bv.w};
                *(float4*)(out + (size_t)(tid * 64 + er) * 64 + mi * 16 + lg * 4) = o;
            }
        }
        __syncthreads();
    }
}

// ---------------- launcher ----------------

extern "C" void kernel_launch(void* const* d_in, const int* in_sizes, int n_in,
                              void* d_out, int out_size, void* d_ws, size_t ws_size,
                              hipStream_t stream) {
    const float* x   = (const float*)d_in[0];
    const int*   ei  = (const int*)d_in[1];
    const float* W1  = (const float*)d_in[2];
    const float* b1  = (const float*)d_in[3];
    const float* W2  = (const float*)d_in[4];
    const float* b2  = (const float*)d_in[5];
    const float* Wp1 = (const float*)d_in[6];
    const float* bp1 = (const float*)d_in[7];
    const float* Wp2 = (const float*)d_in[8];
    const float* bp2 = (const float*)d_in[9];
    const float* Wc  = (const float*)d_in[10];
    const float* bc  = (const float*)d_in[11];

    const int* src = ei;
    const int* dst = ei + N_EDGES;

    float* out    = (float*)d_out;
    float* f_out  = out;                                   // [50000,64]
    float* ef_out = out + (size_t)N_NODES * OUT_DIM;       // [800000,64]
    float* lg_out = ef_out + (size_t)N_EDGES * OUT_DIM;    // [50000,40]
    float* ei_out = lg_out + (size_t)N_NODES * N_CLASSES;  // [2,800000]

    char* p = (char*)d_ws;
    auto alloc = [&](size_t bytes) -> char* {
        char* r = p;
        p += (bytes + 255) / 256 * 256;
        return r;
    };
    unsigned short* h1lin = (unsigned short*)alloc((size_t)N_NODES * HID_DIM * 2);  // 25.6 MB
    unsigned short* h1    = (unsigned short*)alloc((size_t)N_NODES * HID_DIM * 2);  // 25.6 MB
    float*          h2lin = (float*)alloc((size_t)N_NODES * OUT_DIM * 4);           // 12.8 MB
    unsigned short* fb    = (unsigned short*)alloc((size_t)N_NODES * OUT_DIM * 2);  // 6.4 MB
    int*   degi    = (int*)alloc((size_t)N_NODES * 4);
    float* dinv    = (float*)alloc((size_t)N_NODES * 4);
    int*   csr_off = (int*)alloc((size_t)(N_NODES + 1) * 4);
    int*   cursor  = (int*)alloc((size_t)N_NODES * 4);
    int*   csr_src = (int*)alloc((size_t)N_EDGES * 4);
    int*   bsum    = (int*)alloc(256 * 4);
    short* W1t     = (short*)alloc((size_t)256 * 128 * 2);
    short* W2t     = (short*)alloc((size_t)64 * 256 * 2);
    short* Wp1t    = (short*)alloc((size_t)256 * 128 * 2);
    short* Wp2t    = (short*)alloc((size_t)64 * 256 * 2);

    const int nbScan = (N_NODES + 255) / 256;  // 196

    hipMemsetAsync(degi, 0, (size_t)N_NODES * 4, stream);
    hipMemsetAsync(cursor, 0, (size_t)N_NODES * 4, stream);

    k_deg_count<<<(N_EDGES + 255) / 256, 256, 0, stream>>>(dst, degi);
    k_dinv<<<nbScan, 256, 0, stream>>>(degi, dinv);
    k_scan_bsum<<<nbScan, 256, 0, stream>>>(degi, N_NODES, bsum);
    k_scan_bscan<<<1, 256, 0, stream>>>(bsum, nbScan);
    k_scan_final<<<nbScan, 256, 0, stream>>>(degi, N_NODES, bsum, csr_off);
    k_csr_fill<<<(N_EDGES + 255) / 256, 256, 0, stream>>>(src, dst, csr_off, cursor, csr_src);

    k_prep_w<<<128, 256, 0, stream>>>(W1, W2, Wp1, Wp2, W1t, W2t, Wp1t, Wp2t);

    const int nbG = (N_NODES + 63) / 64;  // 782
    k_gemm1_mfma<<<nbG, 256, 0, stream>>>(x, W1t, h1lin);
    k_agg1<<<N_NODES / 4, 256, 0, stream>>>(h1lin, dinv, csr_off, csr_src, b1, h1);
    k_gemm2_mfma<<<nbG, 256, 0, stream>>>(h1, W2t, h2lin);
    k_agg2<<<N_NODES / 4, 256, 0, stream>>>(h2lin, dinv, csr_off, csr_src, b2, f_out, fb);

    k_logits<<<N_NODES / 16, 256, 0, stream>>>(f_out, Wc, bc, lg_out);
    k_edge_mlp3<<<768, 256, 0, stream>>>(fb, src, dst, Wp1t, bp1, Wp2t, bp2, ef_out, N_EDGES / 64);
    k_copy_ei<<<(2 * N_EDGES / 4 + 255) / 256, 256, 0, stream>>>(ei, ei_out);
}

// Round 4
// 520.975 us; speedup vs baseline: 1.5171x; 1.5171x over previous
//
#include <hip/hip_runtime.h>

#define N_NODES   50000
#define N_EDGES   800000
#define IN_DIM    128
#define HID_DIM   256
#define OUT_DIM   64
#define N_CLASSES 40

typedef __attribute__((ext_vector_type(8))) short short8;
typedef __attribute__((ext_vector_type(8))) unsigned short ushort8;
typedef __attribute__((ext_vector_type(4))) float f32x4;

__device__ inline short f2bf(float x) {
    unsigned u = __builtin_bit_cast(unsigned, x);
    unsigned r = (u + 0x7FFFu + ((u >> 16) & 1u)) >> 16;
    return (short)r;
}
__device__ inline float bf2f(unsigned short u) {
    unsigned v = ((unsigned)u) << 16;
    return __builtin_bit_cast(float, v);
}

// ---------------- degree / normalization / CSR ----------------

__global__ void k_deg_count(const int* __restrict__ dst, int* __restrict__ degi) {
    int e = blockIdx.x * 256 + threadIdx.x;
    if (e < N_EDGES) atomicAdd(&degi[dst[e]], 1);
}

__global__ void k_dinv(const int* __restrict__ degi, float* __restrict__ dinv) {
    int v = blockIdx.x * 256 + threadIdx.x;
    if (v < N_NODES) dinv[v] = rsqrtf((float)(degi[v] + 1));
}

__global__ void k_scan_bsum(const int* __restrict__ vals, int n, int* __restrict__ bsum) {
    __shared__ int sm[256];
    int t = threadIdx.x, i = blockIdx.x * 256 + t;
    sm[t] = (i < n) ? vals[i] : 0;
    __syncthreads();
    for (int s = 128; s > 0; s >>= 1) {
        if (t < s) sm[t] += sm[t + s];
        __syncthreads();
    }
    if (t == 0) bsum[blockIdx.x] = sm[0];
}

__global__ void k_scan_bscan(int* __restrict__ bsum, int nb) {
    __shared__ int sm[256];
    int t = threadIdx.x;
    int orig = (t < nb) ? bsum[t] : 0;
    sm[t] = orig;
    __syncthreads();
    for (int off = 1; off < 256; off <<= 1) {
        int v = (t >= off) ? sm[t - off] : 0;
        __syncthreads();
        sm[t] += v;
        __syncthreads();
    }
    if (t < nb) bsum[t] = sm[t] - orig;
}

__global__ void k_scan_final(const int* __restrict__ vals, int n,
                             const int* __restrict__ bscan, int* __restrict__ out) {
    __shared__ int sm[256];
    int t = threadIdx.x, i = blockIdx.x * 256 + t;
    int orig = (i < n) ? vals[i] : 0;
    sm[t] = orig;
    __syncthreads();
    for (int off = 1; off < 256; off <<= 1) {
        int v = (t >= off) ? sm[t - off] : 0;
        __syncthreads();
        sm[t] += v;
        __syncthreads();
    }
    int excl = sm[t] - orig + bscan[blockIdx.x];
    if (i < n) out[i] = excl;
    if (i == n - 1) out[n] = excl + orig;
}

__global__ void k_csr_fill(const int* __restrict__ src, const int* __restrict__ dst,
                           const int* __restrict__ csr_off, int* __restrict__ cursor,
                           int* __restrict__ csr_src, int* __restrict__ csr_dst,
                           int* __restrict__ csr_eid) {
    int e = blockIdx.x * 256 + threadIdx.x;
    if (e < N_EDGES) {
        int d = dst[e];
        int pos = csr_off[d] + atomicAdd(&cursor[d], 1);
        csr_src[pos] = src[e];
        csr_dst[pos] = d;
        csr_eid[pos] = e;
    }
}

// ---------------- weight prep: fp32 [K][N] -> bf16 [N][K] ----------------

__global__ void k_prep_w(const float* __restrict__ W1, const float* __restrict__ W2,
                         const float* __restrict__ Wp1, const float* __restrict__ Wp2,
                         short* __restrict__ W1t, short* __restrict__ W2t,
                         short* __restrict__ Wp1t, short* __restrict__ Wp2t) {
    int i = blockIdx.x * 256 + threadIdx.x;
    if (i < 128 * 256) {  // [128][256] -> [256][128]
        int k = i >> 8, n = i & 255;
        W1t[n * 128 + k]  = f2bf(W1[i]);
        Wp1t[n * 128 + k] = f2bf(Wp1[i]);
    }
    if (i < 256 * 64) {   // [256][64] -> [64][256]
        int k = i >> 6, o = i & 63;
        W2t[o * 256 + k]  = f2bf(W2[i]);
        Wp2t[o * 256 + k] = f2bf(Wp2[i]);
    }
}

__global__ void k_x2bf(const float* __restrict__ x, unsigned short* __restrict__ xb) {
    int i = blockIdx.x * 256 + threadIdx.x;
    if (i < N_NODES * IN_DIM / 4) {
        float4 v = ((const float4*)x)[i];
        ushort4 u;
        u.x = (unsigned short)f2bf(v.x); u.y = (unsigned short)f2bf(v.y);
        u.z = (unsigned short)f2bf(v.z); u.w = (unsigned short)f2bf(v.w);
        ((ushort4*)xb)[i] = u;
    }
}

__global__ void k_copy_ei(const int* __restrict__ ei, float* __restrict__ out) {
    int j = blockIdx.x * 256 + threadIdx.x;
    if (j < (2 * N_EDGES) / 4) {
        int4 v = ((const int4*)ei)[j];
        float4 o = {(float)v.x, (float)v.y, (float)v.z, (float)v.w};
        ((float4*)out)[j] = o;
    }
}

// ---------------- agg0: xa = Anorm * xb  (128-dim bf16, wave/node, 2 ch/lane) ----

__global__ __launch_bounds__(256) void k_agg0(const unsigned short* __restrict__ xb,
                                              const float* __restrict__ dinv,
                                              const int* __restrict__ csr_off,
                                              const int* __restrict__ csr_src,
                                              unsigned short* __restrict__ xa) {
    const int v = blockIdx.x * 4 + (threadIdx.x >> 6);
    const int lane = threadIdx.x & 63;
    float dv = dinv[v];
    unsigned c = *(const unsigned*)(xb + (size_t)v * 128 + lane * 2);
    float a0 = bf2f((unsigned short)(c & 0xFFFF)) * dv;
    float a1 = bf2f((unsigned short)(c >> 16)) * dv;
    int beg = csr_off[v], end = csr_off[v + 1];
    for (int base = beg; base < end; base += 64) {
        int idx = base + lane;
        int sj = (idx < end) ? csr_src[idx] : 0;
        float dj = (idx < end) ? dinv[sj] : 0.f;
        int m = min(64, end - base);
        for (int j = 0; j < m; j++) {
            int s = __shfl(sj, j);
            float ds = __shfl(dj, j);
            unsigned hv = *(const unsigned*)(xb + (size_t)s * 128 + lane * 2);
            a0 += bf2f((unsigned short)(hv & 0xFFFF)) * ds;
            a1 += bf2f((unsigned short)(hv >> 16)) * ds;
        }
    }
    unsigned o = (unsigned)(unsigned short)f2bf(a0 * dv) |
                 ((unsigned)(unsigned short)f2bf(a1 * dv) << 16);
    *(unsigned*)(xa + (size_t)v * 128 + lane * 2) = o;
}

// ---------------- agg2: f = Anorm * h2 + b2 (64-dim bf16 in, fp32+bf16 out) ----

__global__ __launch_bounds__(256) void k_agg2(const unsigned short* __restrict__ h2b,
                                              const float* __restrict__ dinv,
                                              const int* __restrict__ csr_off,
                                              const int* __restrict__ csr_src,
                                              const float* __restrict__ b2,
                                              float* __restrict__ f_out,
                                              unsigned short* __restrict__ fb) {
    const int v = blockIdx.x * 4 + (threadIdx.x >> 6);
    const int lane = threadIdx.x & 63;
    float dv = dinv[v];
    float acc = bf2f(h2b[(size_t)v * 64 + lane]) * dv;
    int beg = csr_off[v], end = csr_off[v + 1];
    for (int base = beg; base < end; base += 64) {
        int idx = base + lane;
        int sj = (idx < end) ? csr_src[idx] : 0;
        float dj = (idx < end) ? dinv[sj] : 0.f;
        int m = min(64, end - base);
        for (int j = 0; j < m; j++) {
            int s = __shfl(sj, j);
            float ds = __shfl(dj, j);
            acc += bf2f(h2b[(size_t)s * 64 + lane]) * ds;
        }
    }
    float r = acc * dv + b2[lane];
    f_out[(size_t)v * 64 + lane] = r;
    fb[(size_t)v * 64 + lane] = (unsigned short)f2bf(r);
}

// ---------------- GEMM1: h1 = relu(xa @ W1 + b1)  bf16 -> bf16 ----------------

__global__ __launch_bounds__(256) void k_gemm1_mfma(const unsigned short* __restrict__ xa,
                                                    const short* __restrict__ W1t,
                                                    const float* __restrict__ b1,
                                                    unsigned short* __restrict__ h1) {
    __shared__ unsigned short xs[64 * 128];  // 16 KB
    const int t = threadIdx.x;
    const int lane = t & 63, wv = t >> 6, lr = lane & 15, lg = lane >> 4;
    const int nb = blockIdx.x * 64;

    #pragma unroll
    for (int i = 0; i < 4; i++) {
        int q = t + i * 256, row = q >> 4, seg = q & 15;
        int node = nb + row;
        ushort8 v = {0, 0, 0, 0, 0, 0, 0, 0};
        if (node < N_NODES) v = *(const ushort8*)(xa + (size_t)node * 128 + seg * 8);
        *(ushort8*)((char*)xs + ((row * 256 + seg * 16) ^ ((row & 7) << 4))) = v;
    }

    short8 A1[4][4];
    #pragma unroll
    for (int mi = 0; mi < 4; mi++)
        #pragma unroll
        for (int kt = 0; kt < 4; kt++)
            A1[mi][kt] = *(const short8*)(W1t + (size_t)(wv * 64 + mi * 16 + lr) * 128 + kt * 32 + lg * 8);
    __syncthreads();

    #pragma unroll
    for (int nj = 0; nj < 4; nj++) {
        short8 Bf[4];
        int nr = nj * 16 + lr;
        #pragma unroll
        for (int kt = 0; kt < 4; kt++)
            Bf[kt] = *(const short8*)((const char*)xs + ((nr * 256 + kt * 64 + lg * 16) ^ ((nr & 7) << 4)));
        int node = nb + nr;
        #pragma unroll
        for (int mi = 0; mi < 4; mi++) {
            f32x4 acc = {0.f, 0.f, 0.f, 0.f};
            #pragma unroll
            for (int kt = 0; kt < 4; kt++)
                acc = __builtin_amdgcn_mfma_f32_16x16x32_bf16(A1[mi][kt], Bf[kt], acc, 0, 0, 0);
            if (node < N_NODES) {
                float4 bv = *(const float4*)(b1 + wv * 64 + mi * 16 + lg * 4);
                ushort4 u;
                u.x = (unsigned short)f2bf(fmaxf(acc[0] + bv.x, 0.f));
                u.y = (unsigned short)f2bf(fmaxf(acc[1] + bv.y, 0.f));
                u.z = (unsigned short)f2bf(fmaxf(acc[2] + bv.z, 0.f));
                u.w = (unsigned short)f2bf(fmaxf(acc[3] + bv.w, 0.f));
                *(ushort4*)(h1 + (size_t)node * 256 + wv * 64 + mi * 16 + lg * 4) = u;
            }
        }
    }
}

// ---------------- GEMM2: h2b = h1 @ W2  bf16 -> bf16 (no bias) ----------------

__global__ __launch_bounds__(256) void k_gemm2_mfma(const unsigned short* __restrict__ h1,
                                                    const short* __restrict__ W2t,
                                                    unsigned short* __restrict__ h2b) {
    __shared__ unsigned short hs[64 * 256];  // 32 KB
    const int t = threadIdx.x;
    const int lane = t & 63, wv = t >> 6, lr = lane & 15, lg = lane >> 4;
    const int nb = blockIdx.x * 64;

    #pragma unroll
    for (int i = 0; i < 8; i++) {
        int q = t + i * 256, row = q >> 5, seg = q & 31;
        int node = nb + row;
        ushort8 v = {0, 0, 0, 0, 0, 0, 0, 0};
        if (node < N_NODES) v = *(const ushort8*)(h1 + (size_t)node * 256 + seg * 8);
        *(ushort8*)((char*)hs + ((row * 512 + seg * 16) ^ ((row & 7) << 4))) = v;
    }

    short8 A2[8];  // W2t rows wv*16+lr
    #pragma unroll
    for (int kt = 0; kt < 8; kt++)
        A2[kt] = *(const short8*)(W2t + (size_t)(wv * 16 + lr) * 256 + kt * 32 + lg * 8);
    __syncthreads();

    #pragma unroll
    for (int nj = 0; nj < 4; nj++) {
        short8 Bh[8];
        int nr = nj * 16 + lr;
        #pragma unroll
        for (int kt = 0; kt < 8; kt++)
            Bh[kt] = *(const short8*)((const char*)hs + ((nr * 512 + kt * 64 + lg * 16) ^ ((nr & 7) << 4)));
        int node = nb + nr;
        f32x4 acc = {0.f, 0.f, 0.f, 0.f};
        #pragma unroll
        for (int kt = 0; kt < 8; kt++)
            acc = __builtin_amdgcn_mfma_f32_16x16x32_bf16(A2[kt], Bh[kt], acc, 0, 0, 0);
        if (node < N_NODES) {
            ushort4 u;
            u.x = (unsigned short)f2bf(acc[0]); u.y = (unsigned short)f2bf(acc[1]);
            u.z = (unsigned short)f2bf(acc[2]); u.w = (unsigned short)f2bf(acc[3]);
            *(ushort4*)(h2b + (size_t)node * 64 + wv * 16 + lg * 4) = u;
        }
    }
}

// ---------------- classifier head: 16 nodes/block ----------------

__global__ __launch_bounds__(256) void k_logits(const float* __restrict__ f,
                                                const float* __restrict__ Wc,
                                                const float* __restrict__ bc,
                                                float* __restrict__ out) {
    __shared__ float fs[16 * 64];
    __shared__ float Wcs[64 * 40];
    __shared__ float bcs[40];
    const int t = threadIdx.x;
    const int nb = blockIdx.x * 16;
    {
        float4 v = ((const float4*)f)[(size_t)(nb + (t >> 4)) * 16 + (t & 15)];
        *(float4*)(fs + t * 4) = v;
    }
    #pragma unroll
    for (int k = 0; k < 10; k++) Wcs[t + k * 256] = Wc[t + k * 256];
    if (t < 40) bcs[t] = bc[t];
    __syncthreads();
    #pragma unroll
    for (int k = 0; k < 3; k++) {
        int idx = t + k * 256;
        if (idx < 640) {
            int n = idx / 40, cls = idx - n * 40;
            float acc = bcs[cls];
            #pragma unroll
            for (int i = 0; i < 64; i++) acc += fs[n * 64 + i] * Wcs[i * 40 + cls];
            out[(size_t)(nb + n) * 40 + cls] = acc;
        }
    }
}

// ---------------- fused edge MLP: CSR-ordered, non-persistent, 64 pos/block ----
// dst side of gather is sequential (CSR buckets) -> L1/L2 hits; src side random.
// Output scattered by original edge id (full 256-B rows).

__global__ __launch_bounds__(256, 3) void k_edge_mlp4(
        const unsigned short* __restrict__ fb,
        const int* __restrict__ csr_src, const int* __restrict__ csr_dst,
        const int* __restrict__ csr_eid,
        const short* __restrict__ Wp1t, const float* __restrict__ bp1,
        const short* __restrict__ Wp2t, const float* __restrict__ bp2,
        float* __restrict__ out) {
    __shared__ unsigned short ef_s[64 * 128];   // 16 KB
    __shared__ unsigned short hid_s[64 * 256];  // 32 KB
    __shared__ int s_src[64], s_dst[64], s_eid[64];

    const int t = threadIdx.x;
    const int lane = t & 63, wv = t >> 6, lr = lane & 15, lg = lane >> 4;
    const int p0 = blockIdx.x * 64;

    if (t < 64) {
        s_src[t] = csr_src[p0 + t];
        s_dst[t] = csr_dst[p0 + t];
        s_eid[t] = csr_eid[p0 + t];
    }

    // hoist weight fragments (overlap with idx loads)
    short8 A1[4][4];
    #pragma unroll
    for (int mi = 0; mi < 4; mi++)
        #pragma unroll
        for (int kt = 0; kt < 4; kt++)
            A1[mi][kt] = *(const short8*)(Wp1t + (size_t)(wv * 64 + mi * 16 + lr) * 128 + kt * 32 + lg * 8);
    short8 A2[8];
    #pragma unroll
    for (int kt = 0; kt < 8; kt++)
        A2[kt] = *(const short8*)(Wp2t + (size_t)(wv * 16 + lr) * 256 + kt * 32 + lg * 8);
    __syncthreads();

    // gather: 64 rows x (8 src + 8 dst) 16-B chunks
    ushort8 g[4];
    #pragma unroll
    for (int i = 0; i < 4; i++) {
        int q = t + i * 256, el = q >> 4, seg = q & 15;
        int node = (seg < 8) ? s_src[el] : s_dst[el];
        g[i] = *(const ushort8*)(fb + (size_t)node * 64 + (seg & 7) * 8);
    }
    #pragma unroll
    for (int i = 0; i < 4; i++) {
        int q = t + i * 256, el = q >> 4, seg = q & 15;
        *(ushort8*)((char*)ef_s + ((el * 256 + seg * 16) ^ ((el & 7) << 4))) = g[i];
    }
    __syncthreads();

    // ---- L1: wave owns hidden quarter wv*64 ----
    #pragma unroll
    for (int nj = 0; nj < 4; nj++) {
        short8 Bf[4];
        int er = nj * 16 + lr;
        #pragma unroll
        for (int kt = 0; kt < 4; kt++)
            Bf[kt] = *(const short8*)((const char*)ef_s + ((er * 256 + kt * 64 + lg * 16) ^ ((er & 7) << 4)));
        #pragma unroll
        for (int mi = 0; mi < 4; mi++) {
            f32x4 acc = {0.f, 0.f, 0.f, 0.f};
            #pragma unroll
            for (int kt = 0; kt < 4; kt++)
                acc = __builtin_amdgcn_mfma_f32_16x16x32_bf16(A1[mi][kt], Bf[kt], acc, 0, 0, 0);
            float4 bv = *(const float4*)(bp1 + wv * 64 + mi * 16 + lg * 4);
            ushort4 h4;
            h4.x = (unsigned short)f2bf(fmaxf(acc[0] + bv.x, 0.f));
            h4.y = (unsigned short)f2bf(fmaxf(acc[1] + bv.y, 0.f));
            h4.z = (unsigned short)f2bf(fmaxf(acc[2] + bv.z, 0.f));
            h4.w = (unsigned short)f2bf(fmaxf(acc[3] + bv.w, 0.f));
            *(ushort4*)((char*)hid_s + ((er * 512 + wv * 128 + mi * 32 + lg * 8) ^ ((er & 7) << 4))) = h4;
        }
    }
    __syncthreads();

    // ---- L2: wave owns out quarter wv*16 ----
    float4 bv2 = *(const float4*)(bp2 + wv * 16 + lg * 4);
    #pragma unroll
    for (int nj = 0; nj < 4; nj++) {
        short8 Bh[8];
        int er = nj * 16 + lr;
        #pragma unroll
        for (int kt = 0; kt < 8; kt++)
            Bh[kt] = *(const short8*)((const char*)hid_s + ((er * 512 + kt * 64 + lg * 16) ^ ((er & 7) << 4)));
        f32x4 acc = {0.f, 0.f, 0.f, 0.f};
        #pragma unroll
        for (int kt = 0; kt < 8; kt++)
            acc = __builtin_amdgcn_mfma_f32_16x16x32_bf16(A2[kt], Bh[kt], acc, 0, 0, 0);
        int eid = s_eid[er];
        float4 o = {acc[0] + bv2.x, acc[1] + bv2.y, acc[2] + bv2.z, acc[3] + bv2.w};
        *(float4*)(out + (size_t)eid * 64 + wv * 16 + lg * 4) = o;
    }
}

// ---------------- launcher ----------------

extern "C" void kernel_launch(void* const* d_in, const int* in_sizes, int n_in,
                              void* d_out, int out_size, void* d_ws, size_t ws_size,
                              hipStream_t stream) {
    const float* x   = (const float*)d_in[0];
    const int*   ei  = (const int*)d_in[1];
    const float* W1  = (const float*)d_in[2];
    const float* b1  = (const float*)d_in[3];
    const float* W2  = (const float*)d_in[4];
    const float* b2  = (const float*)d_in[5];
    const float* Wp1 = (const float*)d_in[6];
    const float* bp1 = (const float*)d_in[7];
    const float* Wp2 = (const float*)d_in[8];
    const float* bp2 = (const float*)d_in[9];
    const float* Wc  = (const float*)d_in[10];
    const float* bc  = (const float*)d_in[11];

    const int* src = ei;
    const int* dst = ei + N_EDGES;

    float* out    = (float*)d_out;
    float* f_out  = out;                                   // [50000,64]
    float* ef_out = out + (size_t)N_NODES * OUT_DIM;       // [800000,64]
    float* lg_out = ef_out + (size_t)N_EDGES * OUT_DIM;    // [50000,40]
    float* ei_out = lg_out + (size_t)N_NODES * N_CLASSES;  // [2,800000]

    char* p = (char*)d_ws;
    auto alloc = [&](size_t bytes) -> char* {
        char* r = p;
        p += (bytes + 255) / 256 * 256;
        return r;
    };
    unsigned short* xb   = (unsigned short*)alloc((size_t)N_NODES * IN_DIM * 2);   // 12.8 MB
    unsigned short* xa   = (unsigned short*)alloc((size_t)N_NODES * IN_DIM * 2);   // 12.8 MB
    unsigned short* h1   = (unsigned short*)alloc((size_t)N_NODES * HID_DIM * 2);  // 25.6 MB
    unsigned short* h2b  = (unsigned short*)alloc((size_t)N_NODES * OUT_DIM * 2);  // 6.4 MB
    unsigned short* fb   = (unsigned short*)alloc((size_t)N_NODES * OUT_DIM * 2);  // 6.4 MB
    int*   degi    = (int*)alloc((size_t)N_NODES * 4);
    float* dinv    = (float*)alloc((size_t)N_NODES * 4);
    int*   csr_off = (int*)alloc((size_t)(N_NODES + 1) * 4);
    int*   cursor  = (int*)alloc((size_t)N_NODES * 4);
    int*   csr_src = (int*)alloc((size_t)N_EDGES * 4);
    int*   csr_dst = (int*)alloc((size_t)N_EDGES * 4);
    int*   csr_eid = (int*)alloc((size_t)N_EDGES * 4);
    int*   bsum    = (int*)alloc(256 * 4);
    short* W1t     = (short*)alloc((size_t)256 * 128 * 2);
    short* W2t     = (short*)alloc((size_t)64 * 256 * 2);
    short* Wp1t    = (short*)alloc((size_t)256 * 128 * 2);
    short* Wp2t    = (short*)alloc((size_t)64 * 256 * 2);

    const int nbScan = (N_NODES + 255) / 256;  // 196

    hipMemsetAsync(degi, 0, (size_t)N_NODES * 4, stream);
    hipMemsetAsync(cursor, 0, (size_t)N_NODES * 4, stream);

    k_deg_count<<<(N_EDGES + 255) / 256, 256, 0, stream>>>(dst, degi);
    k_dinv<<<nbScan, 256, 0, stream>>>(degi, dinv);
    k_scan_bsum<<<nbScan, 256, 0, stream>>>(degi, N_NODES, bsum);
    k_scan_bscan<<<1, 256, 0, stream>>>(bsum, nbScan);
    k_scan_final<<<nbScan, 256, 0, stream>>>(degi, N_NODES, bsum, csr_off);
    k_csr_fill<<<(N_EDGES + 255) / 256, 256, 0, stream>>>(src, dst, csr_off, cursor,
                                                          csr_src, csr_dst, csr_eid);

    k_prep_w<<<128, 256, 0, stream>>>(W1, W2, Wp1, Wp2, W1t, W2t, Wp1t, Wp2t);
    k_x2bf<<<(N_NODES * IN_DIM / 4 + 255) / 256, 256, 0, stream>>>(x, xb);

    const int nbG = (N_NODES + 63) / 64;  // 782
    k_agg0<<<N_NODES / 4, 256, 0, stream>>>(xb, dinv, csr_off, csr_src, xa);
    k_gemm1_mfma<<<nbG, 256, 0, stream>>>(xa, W1t, b1, h1);
    k_gemm2_mfma<<<nbG, 256, 0, stream>>>(h1, W2t, h2b);
    k_agg2<<<N_NODES / 4, 256, 0, stream>>>(h2b, dinv, csr_off, csr_src, b2, f_out, fb);

    k_logits<<<N_NODES / 16, 256, 0, stream>>>(f_out, Wc, bc, lg_out);
    k_edge_mlp4<<<N_EDGES / 64, 256, 0, stream>>>(fb, csr_src, csr_dst, csr_eid,
                                                  Wp1t, bp1, Wp2t, bp2, ef_out);
    k_copy_ei<<<(2 * N_EDGES / 4 + 255) / 256, 256, 0, stream>>>(ei, ei_out);
}